// Round 5
// baseline (80.344 us; speedup 1.0000x reference)
//
#include <hip/hip_runtime.h>

// BayesPosLinear: out[s,b,o] = sum_i input[s,b,i] * exp(w_mu[o,i] + (1e-6+softplus(w_std_eta[o,i]))*eps_w[b,o,i])
//                 + (b_mu[o] + (1e-6+softplus(b_std_eta[o]))*eps_b[b,o])
// plus KL(w), KL(b) scalars.
// S=16, B=32, IN=1024, OUT=1024.
//
// R5 structure:
//  - PREPASS: sp table into d_ws + both KLs (unchanged from R4).
//  - MAIN: 1024 blocks (8 xcd * 4 osub * 32 b) x 512 thr. Each block owns 32 contiguous
//    o-rows of one b -> streams a contiguous 128KB chunk of eps_w.
//    Wave = 2 half-waves of 32 lanes; each half owns 2 adjacent o-rows.
//    Per it: 512B-contiguous visits per row, 6 independent dwordx4 in flight (A/B dbuf).
//    __launch_bounds__(512,2) -> 256-reg cap so the pipeline regs survive (R4 collapsed
//    to 64 regs under (512,4) and serialized all loads).
//  - input[b] (64KB) in LDS; ds_read_b128 broadcast 2-way; 128 ds_reads/lane.

constexpr int S_ = 16, B_ = 32, IN_ = 1024, OUT_ = 1024;

__device__ __forceinline__ float softplus_f(float x) {
    float e = __expf(-fabsf(x));
    return fmaxf(x, 0.0f) + __logf(1.0f + e);
}

// ---------------- prepass: sp table + both KLs ----------------
__global__ __launch_bounds__(256) void bpl_pre_kernel(
    const float* __restrict__ w_mu, const float* __restrict__ w_eta,
    const float* __restrict__ b_mu, const float* __restrict__ b_eta,
    float* __restrict__ sp_out,   // [OUT,IN] = softplus(w_eta)+1e-6
    float* __restrict__ kl)       // kl[0]=kl_w, kl[1]=kl_b (pre-zeroed)
{
    __shared__ float red[4];
    const int tid  = threadIdx.x;
    const int wid  = tid >> 6;
    const int lane = tid & 63;

    const size_t base = (size_t)blockIdx.x * IN_ + tid * 4;
    const float4 mu = *reinterpret_cast<const float4*>(&w_mu[base]);
    const float4 et = *reinterpret_cast<const float4*>(&w_eta[base]);
    const float m[4] = {mu.x, mu.y, mu.z, mu.w};
    const float e[4] = {et.x, et.y, et.z, et.w};

    float sp[4];
    float local = 0.0f;
    #pragma unroll
    for (int j = 0; j < 4; ++j) {
        sp[j] = __logf(1.0f + __expf(e[j])) + 1e-6f;   // w_eta in [-4,-2] -> stable
        local += -__logf(sp[j]) + 0.5f * fmaf(sp[j], sp[j], m[j] * m[j]) - 0.5f;
    }
    float4 spv = {sp[0], sp[1], sp[2], sp[3]};
    *reinterpret_cast<float4*>(&sp_out[base]) = spv;

    #pragma unroll
    for (int off = 32; off > 0; off >>= 1) local += __shfl_xor(local, off, 64);
    if (lane == 0) red[wid] = local;
    __syncthreads();
    if (tid == 0) atomicAdd(&kl[0], red[0] + red[1] + red[2] + red[3]);

    if (blockIdx.x != 0) return;

    float lb = 0.0f;
    #pragma unroll
    for (int j = 0; j < 4; ++j) {
        const int idx = tid * 4 + j;
        const float sd = softplus_f(b_eta[idx]) + 1e-6f;
        const float mm = b_mu[idx];
        lb += -__logf(sd) + 0.5f * fmaf(sd, sd, mm * mm) - 0.5f;
    }
    #pragma unroll
    for (int off = 32; off > 0; off >>= 1) lb += __shfl_xor(lb, off, 64);
    __syncthreads();
    if (lane == 0) red[wid] = lb;
    __syncthreads();
    if (tid == 0) atomicAdd(&kl[1], red[0] + red[1] + red[2] + red[3]);
}

// ---------------- main kernel helpers ----------------
template<bool PRE>
__device__ __forceinline__ void wgen4(const float4 sp, const float4 ep, const float4 mu,
                                      float w[4], bool dokl, float& klw)
{
    float s[4];
    if (PRE) {
        s[0] = sp.x; s[1] = sp.y; s[2] = sp.z; s[3] = sp.w;
    } else {
        s[0] = __logf(1.0f + __expf(sp.x)) + 1e-6f;   // here sp = w_eta (<0)
        s[1] = __logf(1.0f + __expf(sp.y)) + 1e-6f;
        s[2] = __logf(1.0f + __expf(sp.z)) + 1e-6f;
        s[3] = __logf(1.0f + __expf(sp.w)) + 1e-6f;
    }
    const float epv[4] = {ep.x, ep.y, ep.z, ep.w};
    const float muv[4] = {mu.x, mu.y, mu.z, mu.w};
    #pragma unroll
    for (int j = 0; j < 4; ++j) {
        w[j] = __expf(fmaf(s[j], epv[j], muv[j]));
        if (!PRE && dokl)
            klw += -__logf(s[j]) + 0.5f * fmaf(s[j], s[j], muv[j] * muv[j]) - 0.5f;
    }
}

// ---------------- main batched-linear kernel ----------------
// grid: 1024 blocks (8 xcd * 4 osub * 32 b), 512 threads (8 waves).
// wave: og=lane>>5 in {0,1} -> rows (o0, o0+1) with o0 = o_base + wid*4 + og*2.
template<bool PRE>
__global__ __launch_bounds__(512, 2) void bpl_main_kernel(
    const float* __restrict__ input,   // [S,B,IN]
    const float* __restrict__ w_mu,    // [OUT,IN]
    const float* __restrict__ w_sp,    // PRE ? sp table : w_eta
    const float* __restrict__ b_mu,    // [OUT]
    const float* __restrict__ b_eta,   // [OUT]
    const float* __restrict__ eps_w,   // [B,OUT,IN]
    const float* __restrict__ eps_b,   // [B,OUT]
    float* __restrict__ out,           // [S,B,OUT]
    float* __restrict__ kl)
{
    __shared__ float smem[16384];      // 64KB input[s][i]; overlaid by res[16][34] + kl partials

    const int blk  = blockIdx.x;
    const int xcd  = blk & 7;
    const int rest = blk >> 3;         // 0..127
    const int b    = rest & 31;
    const int osub = rest >> 5;        // 0..3
    const int o_base = xcd * 128 + osub * 32;

    const int tid  = threadIdx.x;
    const int wid  = tid >> 6;         // 0..7
    const int lane = tid & 63;
    const int og   = lane >> 5;        // 0..1
    const int iq   = lane & 31;        // 0..31
    const int o0   = o_base + wid * 4 + og * 2;   // row A; row B = o0+1

    // ---- stage input[b] into LDS ----
    {
        const int s = tid >> 5, c = tid & 31;
        const float* __restrict__ src = input + ((size_t)s * B_ + b) * IN_;
        float* dst = smem + s * 1024;
        #pragma unroll
        for (int j = 0; j < 8; ++j) {
            const int i = c * 4 + j * 128;
            *reinterpret_cast<float4*>(&dst[i]) =
                *reinterpret_cast<const float4*>(&src[i]);
        }
    }
    __syncthreads();

    const float* __restrict__ mu_r0 = w_mu + (size_t)o0 * IN_;
    const float* __restrict__ mu_r1 = mu_r0 + IN_;
    const float* __restrict__ sp_r0 = w_sp + (size_t)o0 * IN_;
    const float* __restrict__ sp_r1 = sp_r0 + IN_;
    const float* __restrict__ ep_r0 = eps_w + ((size_t)b * OUT_ + o0) * IN_;
    const float* __restrict__ ep_r1 = ep_r0 + IN_;

    const bool do_kl = (!PRE) && (b == 0);
    float klw = 0.0f;

    float acc0[16], acc1[16];
    #pragma unroll
    for (int s = 0; s < 16; ++s) { acc0[s] = 0.0f; acc1[s] = 0.0f; }

    const int ib = iq * 4;             // lane offset within a 128-float chunk

    float4 Amu0, Asp0, Aep0, Amu1, Asp1, Aep1;
    float4 Bmu0, Bsp0, Bep0, Bmu1, Bsp1, Bep1;

#define BPL_LOAD(P, IT) do { const int i_ = (IT) * 128 + ib;                              \
        P##mu0 = *reinterpret_cast<const float4*>(mu_r0 + i_);                            \
        P##sp0 = *reinterpret_cast<const float4*>(sp_r0 + i_);                            \
        P##ep0 = *reinterpret_cast<const float4*>(ep_r0 + i_);                            \
        P##mu1 = *reinterpret_cast<const float4*>(mu_r1 + i_);                            \
        P##sp1 = *reinterpret_cast<const float4*>(sp_r1 + i_);                            \
        P##ep1 = *reinterpret_cast<const float4*>(ep_r1 + i_); } while (0)

#define BPL_COMPUTE(P, IT) do {                                                           \
        float w0_[4], w1_[4];                                                             \
        wgen4<PRE>(P##sp0, P##ep0, P##mu0, w0_, do_kl, klw);                              \
        wgen4<PRE>(P##sp1, P##ep1, P##mu1, w1_, do_kl, klw);                              \
        const int off_ = (IT) * 128 + ib;                                                 \
        _Pragma("unroll")                                                                 \
        for (int s_ = 0; s_ < 16; ++s_) {                                                 \
            const float4 v = *reinterpret_cast<const float4*>(&smem[s_ * 1024 + off_]);   \
            acc0[s_] = fmaf(v.x, w0_[0], acc0[s_]);                                       \
            acc0[s_] = fmaf(v.y, w0_[1], acc0[s_]);                                       \
            acc0[s_] = fmaf(v.z, w0_[2], acc0[s_]);                                       \
            acc0[s_] = fmaf(v.w, w0_[3], acc0[s_]);                                       \
            acc1[s_] = fmaf(v.x, w1_[0], acc1[s_]);                                       \
            acc1[s_] = fmaf(v.y, w1_[1], acc1[s_]);                                       \
            acc1[s_] = fmaf(v.z, w1_[2], acc1[s_]);                                       \
            acc1[s_] = fmaf(v.w, w1_[3], acc1[s_]);                                       \
        } } while (0)

    BPL_LOAD(A, 0);
    #pragma unroll
    for (int itp = 0; itp < 4; ++itp) {
        const int itA = itp * 2, itB = itA + 1;
        BPL_LOAD(B, itB);
        BPL_COMPUTE(A, itA);
        if (itp < 3) BPL_LOAD(A, itA + 2);
        BPL_COMPUTE(B, itB);
    }
#undef BPL_LOAD
#undef BPL_COMPUTE

    // ---- reduce each acc across the 32-lane half-wave (5 butterfly steps) ----
    #pragma unroll
    for (int s = 0; s < 16; ++s) {
        float v = acc0[s];
        v += __shfl_xor(v, 1, 32); v += __shfl_xor(v, 2, 32);
        v += __shfl_xor(v, 4, 32); v += __shfl_xor(v, 8, 32);
        v += __shfl_xor(v, 16, 32);
        acc0[s] = v;
        v = acc1[s];
        v += __shfl_xor(v, 1, 32); v += __shfl_xor(v, 2, 32);
        v += __shfl_xor(v, 4, 32); v += __shfl_xor(v, 8, 32);
        v += __shfl_xor(v, 16, 32);
        acc1[s] = v;
    }
    // lane (sl = lane&15, m = (lane>>4)&1) keeps out[s=sl][o = o0+m]
    const int sl = lane & 15, m = (lane >> 4) & 1;
    float rA = acc0[0], rB = acc1[0];
    #pragma unroll
    for (int s = 1; s < 16; ++s) {
        rA = (sl == s) ? acc0[s] : rA;
        rB = (sl == s) ? acc1[s] : rB;
    }
    const float mine = m ? rB : rA;

    if (do_kl) {
        #pragma unroll
        for (int off = 32; off > 0; off >>= 1) klw += __shfl_xor(klw, off, 64);
    }

    __syncthreads();                   // input LDS reads done; overlay

    const int col = wid * 4 + og * 2 + m;    // 0..31
    smem[sl * 34 + col] = mine;
    if (do_kl && lane == 0) smem[576 + wid] = klw;

    if (!PRE && blk == 0) {            // kl_b
        float klb = 0.0f;
        #pragma unroll
        for (int h = 0; h < 2; ++h) {
            const int oo = tid + h * 512;
            const float sd = softplus_f(b_eta[oo]) + 1e-6f;
            const float mm = b_mu[oo];
            klb += -__logf(sd) + 0.5f * fmaf(sd, sd, mm * mm) - 0.5f;
        }
        #pragma unroll
        for (int off = 32; off > 0; off >>= 1) klb += __shfl_xor(klb, off, 64);
        if (lane == 0) smem[592 + wid] = klb;
    }
    __syncthreads();

    // ---- coalesced stores with fused bias: one value per thread ----
    {
        const int s = tid >> 5, c = tid & 31;
        const int oo = o_base + c;
        const float bias = fmaf(softplus_f(b_eta[oo]) + 1e-6f,
                                eps_b[(size_t)b * OUT_ + oo], b_mu[oo]);
        out[((size_t)s * B_ + b) * OUT_ + oo] = smem[s * 34 + c] + bias;
    }

    if (!PRE && do_kl && tid == 0) {
        float t = 0.0f;
        #pragma unroll
        for (int k = 0; k < 8; ++k) t += smem[576 + k];
        atomicAdd(&kl[0], t);
    }
    if (!PRE && blk == 0 && tid == 64) {
        float t = 0.0f;
        #pragma unroll
        for (int k = 0; k < 8; ++k) t += smem[592 + k];
        atomicAdd(&kl[1], t);
    }
}

extern "C" void kernel_launch(void* const* d_in, const int* in_sizes, int n_in,
                              void* d_out, int out_size, void* d_ws, size_t ws_size,
                              hipStream_t stream)
{
    const float* input = (const float*)d_in[0];
    const float* w_mu  = (const float*)d_in[1];
    const float* w_eta = (const float*)d_in[2];
    const float* b_mu  = (const float*)d_in[3];
    const float* b_eta = (const float*)d_in[4];
    const float* eps_w = (const float*)d_in[5];
    const float* eps_b = (const float*)d_in[6];

    float* out = (float*)d_out;
    float* kl  = out + (size_t)S_ * B_ * OUT_;   // offsets 524288, 524289

    hipMemsetAsync(kl, 0, 2 * sizeof(float), stream);

    const size_t SP_BYTES = (size_t)OUT_ * IN_ * sizeof(float);
    if (ws_size >= SP_BYTES) {
        float* sp = (float*)d_ws;
        bpl_pre_kernel<<<1024, 256, 0, stream>>>(w_mu, w_eta, b_mu, b_eta, sp, kl);
        bpl_main_kernel<true><<<1024, 512, 0, stream>>>(input, w_mu, sp, b_mu, b_eta,
                                                        eps_w, eps_b, out, kl);
    } else {
        bpl_main_kernel<false><<<1024, 512, 0, stream>>>(input, w_mu, w_eta, b_mu, b_eta,
                                                         eps_w, eps_b, out, kl);
    }
}

// Round 6
// 73.775 us; speedup vs baseline: 1.0890x; 1.0890x over previous
//
#include <hip/hip_runtime.h>

// BayesPosLinear via MFMA:
//   out[s,b,o] = sum_i input[s,b,i] * exp(w_mu[o,i] + (1e-6+softplus(w_std_eta[o,i]))*eps_w[b,o,i])
//                + (b_mu[o] + (1e-6+softplus(b_std_eta[o]))*eps_b[b,o])
//   + KL(w), KL(b) scalars.
// S=16, B=32, IN=1024, OUT=1024.
//
// R6: 32 GEMMs of [16 x 1024] x [1024 x 1024]^T -> mfma_f32_16x16x32_bf16, M=16=S.
//  - PREPASS: sp table (softplus(w_eta)+1e-6) into d_ws + both KLs (as R4/R5).
//  - MAIN: 512 blocks (8 xcd * 2 * 32 b) x 256 thr (4 waves). Wave owns one 16-o tile.
//    Per k-step(32): lane loads its own B-frag slot (8 f32 of mu/sp/eps, 2 dwordx4 each,
//    128B-contiguous per o-row across lane groups), computes w=exp(fma(sp,eps,mu)),
//    casts bf16 -> one MFMA. A-frag: input[b] staged once into LDS in MFMA-tile order
//    (chunk c = kt*64+lane), so per k-step the wave does ONE contiguous conflict-free
//    ds_read_b128 (addr = lane*16 + kt*1024).
//  - Epilogue: D lane layout (row=(l>>4)*4+r, col=l&15) stores directly, bias fused.
//    No shuffles, no second barrier.

constexpr int S_ = 16, B_ = 32, IN_ = 1024, OUT_ = 1024;

typedef __bf16 bf16x8 __attribute__((ext_vector_type(8)));
typedef float  f32x4  __attribute__((ext_vector_type(4)));

__device__ __forceinline__ float softplus_f(float x) {
    float e = __expf(-fabsf(x));
    return fmaxf(x, 0.0f) + __logf(1.0f + e);
}

// ---------------- prepass: sp table (optional) + both KLs ----------------
template<bool WRITE_SP>
__global__ __launch_bounds__(256) void bpl_pre_kernel(
    const float* __restrict__ w_mu, const float* __restrict__ w_eta,
    const float* __restrict__ b_mu, const float* __restrict__ b_eta,
    float* __restrict__ sp_out,   // [OUT,IN] = softplus(w_eta)+1e-6 (if WRITE_SP)
    float* __restrict__ kl)       // kl[0]=kl_w, kl[1]=kl_b (pre-zeroed)
{
    __shared__ float red[4];
    const int tid  = threadIdx.x;
    const int wid  = tid >> 6;
    const int lane = tid & 63;

    const size_t base = (size_t)blockIdx.x * IN_ + tid * 4;
    const float4 mu = *reinterpret_cast<const float4*>(&w_mu[base]);
    const float4 et = *reinterpret_cast<const float4*>(&w_eta[base]);
    const float m[4] = {mu.x, mu.y, mu.z, mu.w};
    const float e[4] = {et.x, et.y, et.z, et.w};

    float sp[4];
    float local = 0.0f;
    #pragma unroll
    for (int j = 0; j < 4; ++j) {
        sp[j] = __logf(1.0f + __expf(e[j])) + 1e-6f;   // w_eta in [-4,-2] -> stable
        local += -__logf(sp[j]) + 0.5f * fmaf(sp[j], sp[j], m[j] * m[j]) - 0.5f;
    }
    if (WRITE_SP) {
        float4 spv = {sp[0], sp[1], sp[2], sp[3]};
        *reinterpret_cast<float4*>(&sp_out[base]) = spv;
    }

    #pragma unroll
    for (int off = 32; off > 0; off >>= 1) local += __shfl_xor(local, off, 64);
    if (lane == 0) red[wid] = local;
    __syncthreads();
    if (tid == 0) atomicAdd(&kl[0], red[0] + red[1] + red[2] + red[3]);

    if (blockIdx.x != 0) return;

    float lb = 0.0f;
    #pragma unroll
    for (int j = 0; j < 4; ++j) {
        const int idx = tid * 4 + j;
        const float sd = softplus_f(b_eta[idx]) + 1e-6f;
        const float mm = b_mu[idx];
        lb += -__logf(sd) + 0.5f * fmaf(sd, sd, mm * mm) - 0.5f;
    }
    #pragma unroll
    for (int off = 32; off > 0; off >>= 1) lb += __shfl_xor(lb, off, 64);
    __syncthreads();
    if (lane == 0) red[wid] = lb;
    __syncthreads();
    if (tid == 0) atomicAdd(&kl[1], red[0] + red[1] + red[2] + red[3]);
}

// ---------------- main MFMA kernel ----------------
// grid: 512 blocks (xcd = blk&7 -> o-range; b = (blk>>3)&31; oh = blk>>8), 256 thr.
template<bool PRE>
__global__ __launch_bounds__(256, 4) void bpl_mfma_kernel(
    const float* __restrict__ input,   // [S,B,IN]
    const float* __restrict__ w_mu,    // [OUT,IN]
    const float* __restrict__ w_sp,    // PRE ? sp table : w_eta
    const float* __restrict__ b_mu,    // [OUT]
    const float* __restrict__ b_eta,   // [OUT]
    const float* __restrict__ eps_w,   // [B,OUT,IN]
    const float* __restrict__ eps_b,   // [B,OUT]
    float* __restrict__ out)           // [S,B,OUT]
{
    __shared__ __align__(16) __bf16 alds[16384];   // 32KB: A-frags, chunk c = kt*64 + lane

    const int blk = blockIdx.x;
    const int xcd = blk & 7;
    const int r_  = blk >> 3;          // 0..63
    const int b   = r_ & 31;
    const int oh  = r_ >> 5;           // 0..1
    const int o_base = (xcd * 2 + oh) * 64;

    const int tid  = threadIdx.x;
    const int wid  = tid >> 6;         // 0..3 -> o-tile
    const int lane = tid & 63;

    // ---- stage input[b] into LDS as bf16 in MFMA-tile order ----
    // chunk c (16B) holds A-frag for (kt=c>>6, lane=c&63): s=c&15, kg=(c>>6)*4+((c>>4)&3)
    #pragma unroll
    for (int j = 0; j < 8; ++j) {
        const int c   = tid + j * 256;
        const int s   = c & 15;
        const int kgg = ((c >> 6) << 2) | ((c >> 4) & 3);
        const float* src = input + ((size_t)s * B_ + b) * IN_ + kgg * 8;
        const float4 x0 = *reinterpret_cast<const float4*>(src);
        const float4 x1 = *reinterpret_cast<const float4*>(src + 4);
        bf16x8 v;
        v[0] = (__bf16)x0.x; v[1] = (__bf16)x0.y; v[2] = (__bf16)x0.z; v[3] = (__bf16)x0.w;
        v[4] = (__bf16)x1.x; v[5] = (__bf16)x1.y; v[6] = (__bf16)x1.z; v[7] = (__bf16)x1.w;
        *reinterpret_cast<bf16x8*>(&alds[c * 8]) = v;     // contiguous ds_write_b128
    }
    __syncthreads();

    // B-frag slot of this lane: o-col = lane&15, k-base = (lane>>4)*8
    const int on    = lane & 15;
    const int kg0   = lane >> 4;       // 0..3
    const int o_row = o_base + wid * 16 + on;

    const float* __restrict__ mu_p = w_mu  + (size_t)o_row * IN_ + kg0 * 8;
    const float* __restrict__ sp_p = w_sp  + (size_t)o_row * IN_ + kg0 * 8;
    const float* __restrict__ ep_p = eps_w + ((size_t)b * OUT_ + o_row) * IN_ + kg0 * 8;
    const __bf16* __restrict__ a_p = alds + lane * 8;     // + kt*512 elements

    f32x4 acc = {0.0f, 0.0f, 0.0f, 0.0f};

    float4 Am0, Am1, As0, As1, Ae0, Ae1;
    float4 Bm0, Bm1, Bs0, Bs1, Be0, Be1;

#define BPL_LD(P, KT) do { const int i_ = (KT) * 32;                                      \
        P##m0 = *reinterpret_cast<const float4*>(mu_p + i_);                              \
        P##m1 = *reinterpret_cast<const float4*>(mu_p + i_ + 4);                          \
        P##s0 = *reinterpret_cast<const float4*>(sp_p + i_);                              \
        P##s1 = *reinterpret_cast<const float4*>(sp_p + i_ + 4);                          \
        P##e0 = *reinterpret_cast<const float4*>(ep_p + i_);                              \
        P##e1 = *reinterpret_cast<const float4*>(ep_p + i_ + 4); } while (0)

#define BPL_ST(P, KT) do {                                                                \
        const float mm_[8] = {P##m0.x, P##m0.y, P##m0.z, P##m0.w,                         \
                              P##m1.x, P##m1.y, P##m1.z, P##m1.w};                        \
        const float ss_[8] = {P##s0.x, P##s0.y, P##s0.z, P##s0.w,                         \
                              P##s1.x, P##s1.y, P##s1.z, P##s1.w};                        \
        const float ee_[8] = {P##e0.x, P##e0.y, P##e0.z, P##e0.w,                         \
                              P##e1.x, P##e1.y, P##e1.z, P##e1.w};                        \
        bf16x8 bfrag;                                                                     \
        _Pragma("unroll")                                                                 \
        for (int q = 0; q < 8; ++q) {                                                     \
            const float sp_ = PRE ? ss_[q] : (__logf(1.0f + __expf(ss_[q])) + 1e-6f);     \
            bfrag[q] = (__bf16)__expf(fmaf(sp_, ee_[q], mm_[q]));                         \
        }                                                                                 \
        const bf16x8 afrag = *reinterpret_cast<const bf16x8*>(a_p + (KT) * 512);          \
        acc = __builtin_amdgcn_mfma_f32_16x16x32_bf16(afrag, bfrag, acc, 0, 0, 0);        \
    } while (0)

    BPL_LD(A, 0);
    #pragma unroll
    for (int kp = 0; kp < 16; ++kp) {
        BPL_LD(B, 2 * kp + 1);
        BPL_ST(A, 2 * kp);
        if (kp < 15) BPL_LD(A, 2 * kp + 2);
        BPL_ST(B, 2 * kp + 1);
    }
#undef BPL_LD
#undef BPL_ST

    // ---- epilogue: D[row=(kg0*4+r)][col=on] -> out[s][b][o_row], bias fused ----
    const float bias = fmaf(softplus_f(b_eta[o_row]) + 1e-6f,
                            eps_b[(size_t)b * OUT_ + o_row], b_mu[o_row]);
    #pragma unroll
    for (int rr = 0; rr < 4; ++rr) {
        const int s = kg0 * 4 + rr;
        out[((size_t)s * B_ + b) * OUT_ + o_row] = acc[rr] + bias;
    }
}

extern "C" void kernel_launch(void* const* d_in, const int* in_sizes, int n_in,
                              void* d_out, int out_size, void* d_ws, size_t ws_size,
                              hipStream_t stream)
{
    const float* input = (const float*)d_in[0];
    const float* w_mu  = (const float*)d_in[1];
    const float* w_eta = (const float*)d_in[2];
    const float* b_mu  = (const float*)d_in[3];
    const float* b_eta = (const float*)d_in[4];
    const float* eps_w = (const float*)d_in[5];
    const float* eps_b = (const float*)d_in[6];

    float* out = (float*)d_out;
    float* kl  = out + (size_t)S_ * B_ * OUT_;   // offsets 524288, 524289

    hipMemsetAsync(kl, 0, 2 * sizeof(float), stream);

    const size_t SP_BYTES = (size_t)OUT_ * IN_ * sizeof(float);
    if (ws_size >= SP_BYTES) {
        float* sp = (float*)d_ws;
        bpl_pre_kernel<true><<<1024, 256, 0, stream>>>(w_mu, w_eta, b_mu, b_eta, sp, kl);
        bpl_mfma_kernel<true><<<512, 256, 0, stream>>>(input, w_mu, sp, b_mu, b_eta,
                                                       eps_w, eps_b, out);
    } else {
        bpl_pre_kernel<false><<<1024, 256, 0, stream>>>(w_mu, w_eta, b_mu, b_eta,
                                                        nullptr, kl);
        bpl_mfma_kernel<false><<<512, 256, 0, stream>>>(input, w_mu, w_eta, b_mu, b_eta,
                                                        eps_w, eps_b, out);
    }
}